// Round 16
// baseline (257.839 us; speedup 1.0000x reference)
//
#include <hip/hip_runtime.h>

typedef __bf16 bf16_t;
typedef bf16_t bf16x8 __attribute__((ext_vector_type(8)));
typedef bf16_t bf16x4 __attribute__((ext_vector_type(4)));
typedef float f32x4 __attribute__((ext_vector_type(4)));
typedef unsigned short u16;
typedef unsigned int u32;

#define E_TOT 524288
#define MT 64
#define NBLK (E_TOT / MT)   // 8192

__device__ __forceinline__ u16 f2bf(float f) {
  u32 u = __builtin_bit_cast(u32, f);
  u += 0x7FFFu + ((u >> 16) & 1u);
  return (u16)(u >> 16);
}

__device__ __forceinline__ bf16x8 pack8(f32x4 a, f32x4 b) {
  bf16x8 p;
  p[0] = (bf16_t)a[0]; p[1] = (bf16_t)a[1]; p[2] = (bf16_t)a[2]; p[3] = (bf16_t)a[3];
  p[4] = (bf16_t)b[0]; p[5] = (bf16_t)b[1]; p[6] = (bf16_t)b[2]; p[7] = (bf16_t)b[3];
  return p;
}

__device__ __forceinline__ void gload_lds16(const void* g, void* l) {
  __builtin_amdgcn_global_load_lds(
      (const __attribute__((address_space(1))) u32*)g,
      (__attribute__((address_space(3))) u32*)l, 16, 0, 0);
}

// W1 [384][256] f32 -> 12 chunks (BK=32) of bank-swizzled W1^T bf16 (R7 layout).
// 16-B unit U = c*1024 + n*4 + j holds W1^T[n][c*32 + ((j^((n>>1)&3))*8) .. +8)
__global__ void prep_w1tc(const float* __restrict__ W1, u16* __restrict__ W1Tc) {
  int t = blockIdx.x * 256 + threadIdx.x;  // 0..98303
  if (t < 384 * 256) {
    int U = t >> 3, e = t & 7;
    int c = U >> 10, rem = U & 1023;
    int n = rem >> 2, j = rem & 3;
    int k = c * 32 + ((j ^ ((n >> 1) & 3)) << 3) + e;
    W1Tc[t] = f2bf(W1[k * 256 + n]);
  }
}

// W2F frag-ordered: idx = ((ks*4+n2f)*64+l)*8+e
//   holds W2^T[n2=n2f*16+(l&15)][k=ks*32+(l>>4)*8+e] = W2[k*64+n2]
__global__ void prep_w2f(const float* __restrict__ W2, u16* __restrict__ W2F) {
  int t = blockIdx.x * 256 + threadIdx.x;  // 0..16383
  if (t < 16384) {
    int e   = t & 7;
    int l   = (t >> 3) & 63;
    int n2f = (t >> 9) & 3;
    int ks  = t >> 11;
    int n2 = n2f * 16 + (l & 15);
    int k  = ks * 32 + ((l >> 4) << 3) + e;
    W2F[t] = f2bf(W2[k * 64 + n2]);
  }
}

// Fused: x = [src|dest|edge|u[batch]] (E x 384); h = relu(x@W1+b1); out = h@W2+b2
// ALL staging via global_load_lds (zero staging VGPRs, cannot be sunk by regalloc):
//   A: f32, source-baked XOR swizzle (read 2-way free); W: R7's swizzled layout.
// Both double-buffered, true async depth-2 queue, counted vmcnt(6), drain only at tail.
__global__ void __launch_bounds__(256) edge_fused(
    const float* __restrict__ src, const float* __restrict__ dst,
    const float* __restrict__ ea, const float* __restrict__ u,
    const int* __restrict__ batch, const u16* __restrict__ W1Tc,
    const float* __restrict__ b1, const u16* __restrict__ W2F,
    const float* __restrict__ b2, float* __restrict__ out)
{
  // 49152 B LDS: Af f32 dbuf 2x2048 @byte 0 (16 KB); Wb u16 dbuf 2x8192 @16384 (32 KB).
  // Epilogue: Hs[64][256] bf16 (32 KB) overlays Af + Wb[0].
  __shared__ __align__(16) u16 smem[24576];
  float* Af = (float*)smem;
  u16*   Wb = smem + 8192;
  u16*   Hs = smem;

  const int t    = threadIdx.x;
  const int wid  = t >> 6;
  const int lane = t & 63;
  const int lr   = lane & 15;
  const int lg   = lane >> 4;
  const int e0   = blockIdx.x * MT;

  // ---- A glds source addressing: wave wid stages rows [wid*16, wid*16+16) ----
  // glds i covers rows wid*16+i*8..+8; lane l -> row +(l>>3), LDS 16B-unit j=l&7.
  // LDS[row][j] holds x[row][k-unit j^(row&7)] (swizzle baked in source address).
  const int rl   = lane >> 3;
  const int jl   = lane & 7;
  const int rowA = wid * 16 + rl;
  const int rowB = rowA + 8;
  const int sjA  = jl ^ (rowA & 7);
  const int sjB  = jl ^ (rowB & 7);
  const float* psrcA = src + (size_t)(e0 + rowA) * 128 + sjA * 4;
  const float* psrcB = src + (size_t)(e0 + rowB) * 128 + sjB * 4;
  const float* pdstA = dst + (size_t)(e0 + rowA) * 128 + sjA * 4;
  const float* pdstB = dst + (size_t)(e0 + rowB) * 128 + sjB * 4;
  const float* peaA  = ea + (size_t)(e0 + rowA) * 64 + sjA * 4;
  const float* peaB  = ea + (size_t)(e0 + rowB) * 64 + sjB * 4;
  const float* puA   = u + (size_t)batch[e0 + rowA] * 64 + sjA * 4;
  const float* puB   = u + (size_t)batch[e0 + rowB] * 64 + sjB * 4;

  auto issueA = [&](int c, float* Ad) {   // 2 glds/wave, c compile-time
    const float *qa, *qb;
    if (c < 4)       { qa = psrcA + c * 32;       qb = psrcB + c * 32; }
    else if (c < 8)  { qa = pdstA + (c - 4) * 32; qb = pdstB + (c - 4) * 32; }
    else if (c < 10) { qa = peaA + (c - 8) * 32;  qb = peaB + (c - 8) * 32; }
    else             { qa = puA + (c - 10) * 32;  qb = puB + (c - 10) * 32; }
    gload_lds16(qa, Ad + wid * 512);
    gload_lds16(qb, Ad + wid * 512 + 256);
  };
  auto issueW = [&](int c, u16* Wn) {     // 4 glds/wave (R7-verified layout)
    #pragma unroll
    for (int g = 0; g < 4; ++g) {
      int ub = wid * 256 + g * 64;        // wave-uniform 16B-unit base
      gload_lds16(W1Tc + ((size_t)c * 1024 + ub + lane) * 8, Wn + ub * 8);
    }
  };

  // ---- prologue: sets 0 and 1 in flight (12 glds/wave total) ----
  issueA(0, Af);        issueW(0, Wb);
  issueA(1, Af + 2048); issueW(1, Wb + 8192);

  f32x4 acc[4][4];   // [nf][mf] h^T frags (swapped MFMA)
  #pragma unroll
  for (int i = 0; i < 4; ++i)
    #pragma unroll
    for (int j = 0; j < 4; ++j)
      acc[i][j] = (f32x4){0.f, 0.f, 0.f, 0.f};

  // ---- K loop: 12 chunks of 32; steady gate vmcnt(6); zero staging VGPRs ----
  #pragma unroll
  for (int kb = 0; kb < 12; ++kb) {
    const float* Ac = Af + (kb & 1) * 2048;
    u16* Wc = Wb + (kb & 1) * 8192;

    // set(kb) landed; set(kb+1)'s 6 glds stay in flight
    if (kb < 11) asm volatile("s_waitcnt vmcnt(6)" ::: "memory");
    else         asm volatile("s_waitcnt vmcnt(0)" ::: "memory");
    __builtin_amdgcn_sched_barrier(0);
    __builtin_amdgcn_s_barrier();

    __builtin_amdgcn_s_setprio(1);
    bf16x8 af[4];
    #pragma unroll
    for (int mf = 0; mf < 4; ++mf) {
      int row = mf * 16 + lr;
      f32x4 v0 = *(const f32x4*)(Ac + row * 32 + (((2 * lg)     ^ (row & 7)) << 2));
      f32x4 v1 = *(const f32x4*)(Ac + row * 32 + (((2 * lg + 1) ^ (row & 7)) << 2));
      af[mf] = pack8(v0, v1);   // f32->bf16 on VALU, overlapped with MFMA pipe
    }
    #pragma unroll
    for (int nf = 0; nf < 4; ++nf) {
      int n = wid * 64 + nf * 16 + lr;
      bf16x8 wfr = *(const bf16x8*)&Wc[(n * 4 + (lg ^ ((n >> 1) & 3))) * 8];
      #pragma unroll
      for (int mf = 0; mf < 4; ++mf)
        acc[nf][mf] = __builtin_amdgcn_mfma_f32_16x16x32_bf16(wfr, af[mf], acc[nf][mf], 0, 0, 0);
    }
    __builtin_amdgcn_s_setprio(0);

    // all waves' LDS reads of this buffer pair done before refilling it
    asm volatile("s_waitcnt lgkmcnt(0)" ::: "memory");
    __builtin_amdgcn_s_barrier();
    __builtin_amdgcn_sched_barrier(0);

    // refill the just-read buffers with set kb+2 (async, zero registers)
    if (kb <= 9) {
      issueA(kb + 2, Af + (kb & 1) * 2048);
      issueW(kb + 2, Wb + (kb & 1) * 8192);
    }
  }

  // ---- h^T -> Hs[64][256] bf16; swizzle up = uu ^ ((lr&3)<<2) ----
  #pragma unroll
  for (int nf = 0; nf < 4; ++nf) {
    f32x4 b1v = *(const f32x4*)(b1 + wid * 64 + nf * 16 + lg * 4);
    #pragma unroll
    for (int mf = 0; mf < 4; ++mf) {
      int row = mf * 16 + lr;
      bf16x4 hb;
      #pragma unroll
      for (int rr = 0; rr < 4; ++rr)
        hb[rr] = (bf16_t)fmaxf(acc[nf][mf][rr] + b1v[rr], 0.f);
      int uu = (wid * 4 + nf) * 4 + lg;
      int up = uu ^ ((lr & 3) << 2);
      *(bf16x4*)&Hs[row * 256 + up * 4] = hb;
    }
  }
  asm volatile("s_waitcnt lgkmcnt(0)" ::: "memory");
  __builtin_amdgcn_s_barrier();
  __builtin_amdgcn_sched_barrier(0);

  // ---- layer 2: out^T frags = mfma(W2_frag, h_frag); W2F from L1/L2 ----
  const int row2 = wid * 16 + lr;
  f32x4 d2[4];
  #pragma unroll
  for (int i = 0; i < 4; ++i) d2[i] = (f32x4){0.f, 0.f, 0.f, 0.f};
  #pragma unroll
  for (int ks = 0; ks < 8; ++ks) {
    int uu = ks * 8 + lg * 2;
    int up = uu ^ ((lr & 3) << 2);     // bit0 untouched -> b128 contiguous
    bf16x8 a2 = *(const bf16x8*)&Hs[row2 * 256 + up * 4];
    const u16* q = W2F + (size_t)ks * 2048 + lane * 8;
    #pragma unroll
    for (int n2f = 0; n2f < 4; ++n2f)
      d2[n2f] = __builtin_amdgcn_mfma_f32_16x16x32_bf16(
          *(const bf16x8*)(q + n2f * 512), a2, d2[n2f], 0, 0, 0);
  }

  // ---- epilogue store: f32x4 coalesced ----
  #pragma unroll
  for (int n2f = 0; n2f < 4; ++n2f) {
    f32x4 b2v = *(const f32x4*)(b2 + n2f * 16 + lg * 4);
    f32x4 ov = d2[n2f] + b2v;
    *(f32x4*)&out[(size_t)(e0 + row2) * 64 + n2f * 16 + lg * 4] = ov;
  }
}

extern "C" void kernel_launch(void* const* d_in, const int* in_sizes, int n_in,
                              void* d_out, int out_size, void* d_ws, size_t ws_size,
                              hipStream_t stream) {
  const float* src  = (const float*)d_in[0];
  const float* dst  = (const float*)d_in[1];
  const float* ea   = (const float*)d_in[2];
  const float* u    = (const float*)d_in[3];
  const int* batch  = (const int*)d_in[4];
  const float* W1   = (const float*)d_in[5];
  const float* b1   = (const float*)d_in[6];
  const float* W2   = (const float*)d_in[7];
  const float* b2   = (const float*)d_in[8];
  float* out = (float*)d_out;

  u16* W1Tc = (u16*)d_ws;            // 12 chunks x 1024 16B-units (swizzled W1^T)
  u16* W2F  = W1Tc + 384 * 256;      // 16384 u16 frag-ordered W2^T

  prep_w1tc<<<(384 * 256 + 255) / 256, 256, 0, stream>>>(W1, W1Tc);
  prep_w2f<<<64, 256, 0, stream>>>(W2, W2F);
  edge_fused<<<NBLK, 256, 0, stream>>>(src, dst, ea, u, batch, W1Tc, b1, W2F, b2, out);
}